// Round 6
// baseline (311.620 us; speedup 1.0000x reference)
//
#include <hip/hip_runtime.h>

// 3D spatial transformer (trilinear warp), voxelmorph semantics.
// vol: [B=2, X=160, Y=192, Z=160, C=1] fp32
// trf: [B=2, X=160, Y=192, Z=160, 3]  fp32 (dense displacement)
// out: same shape as vol, fp32.
//
// R10: pure-gather kernel — no LDS, no barriers, no staging.
// Evidence: R8's FETCH (86 MB) is BELOW the 157 MB input ideal -> vol+trf are
// L3-resident across bench iterations; all memory is L3/L2-served. Staging to
// LDS therefore saves nothing and costs the per-block convoy (stage-issue ->
// full vmcnt drain -> barrier) that pinned R4-R9 at 78-100us with every pipe
// idle. Here each thread owns 4 consecutive-z voxels and issues 32
// INDEPENDENT dword gathers (8 corners x 4 voxels) straight from global:
// ~36 outstanding VMEM/wave, zero sync points. Corner gathers of
// consecutive-z voxels share 64B lines; neighboring threads share rows ->
// L1/L2 merge most requests. Chunked XCD swizzle: contiguous x-slabs per
// XCD (~5 MB vol slice ~ per-XCD L2).

#define NXD 160
#define NYD 192
#define NZD 160
#define NVOX (NXD * NYD * NZD)
#define NBATCH 2

#define ZQ (NZD / 4)                     // 40 z-quads per row
#define NQUAD (NBATCH * NXD * NYD * ZQ)  // 614400 quads
#define BLK 256
#define NBLOCKS (NQUAD / BLK)            // 2400

typedef float f4 __attribute__((ext_vector_type(4)));

__global__ __launch_bounds__(BLK)
void warp3d_kernel(const float* __restrict__ vol,
                   const float* __restrict__ trf,
                   float* __restrict__ out) {
    // chunked XCD swizzle (2400 % 8 == 0, bijective): each XCD gets a
    // contiguous run of 300 blocks -> contiguous x-slab -> L2-sized vol slice
    int bid0 = blockIdx.x;
    int bid = (bid0 & 7) * (NBLOCKS / 8) + (bid0 >> 3);

    int q = bid * BLK + threadIdx.x;     // quad index, z fastest
    int zqi = q % ZQ;
    int r   = q / ZQ;
    int y   = r % NYD;
    int r2  = r / NYD;
    int x   = r2 % NXD;
    int b   = r2 / NXD;

    int zb0 = zqi * 4;
    size_t rowb = (((size_t)b * NXD + x) * NYD + y) * NZD + zb0;
    const float* vb = vol + (size_t)b * NVOX;

    // trf: 12 floats = 3 aligned float4 (rowb % 4 == 0 -> 48B-aligned)
    const f4* tv = (const f4*)(trf + rowb * 3);
    f4 t0 = tv[0], t1 = tv[1], t2 = tv[2];

    float dxa[4] = {t0.x, t0.w, t1.z, t2.y};
    float dya[4] = {t0.y, t1.x, t1.w, t2.z};
    float dza[4] = {t0.z, t1.y, t2.x, t2.w};

    float res[4];
#pragma unroll
    for (int j = 0; j < 4; ++j) {
        float lx = fminf(fmaxf((float)x + dxa[j], 0.0f), (float)(NXD - 1));
        float ly = fminf(fmaxf((float)y + dya[j], 0.0f), (float)(NYD - 1));
        float lz = fminf(fmaxf((float)(zb0 + j) + dza[j], 0.0f), (float)(NZD - 1));
        float fx = floorf(lx), fy = floorf(ly), fz = floorf(lz);
        int x0 = (int)fx, y0 = (int)fy, z0 = (int)fz;
        // lower-corner weights d1 = loc1 - loc (0 at clamped top border)
        float wx0 = fminf(fx + 1.0f, (float)(NXD - 1)) - lx;
        float wy0 = fminf(fy + 1.0f, (float)(NYD - 1)) - ly;
        float wz0 = fminf(fz + 1.0f, (float)(NZD - 1)) - lz;

        int x1 = min(x0 + 1, NXD - 1);
        int y1 = min(y0 + 1, NYD - 1);
        int z1 = min(z0 + 1, NZD - 1);
        size_t o00 = (size_t)(x0 * NYD + y0) * NZD;
        size_t o01 = (size_t)(x0 * NYD + y1) * NZD;
        size_t o10 = (size_t)(x1 * NYD + y0) * NZD;
        size_t o11 = (size_t)(x1 * NYD + y1) * NZD;

        float v000 = vb[o00 + z0], v001 = vb[o00 + z1];
        float v010 = vb[o01 + z0], v011 = vb[o01 + z1];
        float v100 = vb[o10 + z0], v101 = vb[o10 + z1];
        float v110 = vb[o11 + z0], v111 = vb[o11 + z1];

        float wx1 = 1.0f - wx0, wy1 = 1.0f - wy0, wz1 = 1.0f - wz0;
        res[j] = wx0 * (wy0 * (wz0 * v000 + wz1 * v001) +
                        wy1 * (wz0 * v010 + wz1 * v011)) +
                 wx1 * (wy0 * (wz0 * v100 + wz1 * v101) +
                        wy1 * (wz0 * v110 + wz1 * v111));
    }

    f4 o;
    o.x = res[0]; o.y = res[1]; o.z = res[2]; o.w = res[3];
    *(f4*)(out + rowb) = o;
}

extern "C" void kernel_launch(void* const* d_in, const int* in_sizes, int n_in,
                              void* d_out, int out_size, void* d_ws, size_t ws_size,
                              hipStream_t stream) {
    const float* vol = (const float*)d_in[0];
    const float* trf = (const float*)d_in[1];
    float* out = (float*)d_out;

    warp3d_kernel<<<NBLOCKS, BLK, 0, stream>>>(vol, trf, out);
}

// Round 7
// 221.975 us; speedup vs baseline: 1.4038x; 1.4038x over previous
//
#include <hip/hip_runtime.h>

// 3D spatial transformer (trilinear warp), voxelmorph semantics.
// vol: [B=2, X=160, Y=192, Z=160, C=1] fp32
// trf: [B=2, X=160, Y=192, Z=160, 3]  fp32 (dense displacement)
// out: same shape as vol, fp32.
//
// R11: many small windows in flight. R4-R10 evidence: staged variants pinned
// at 78-81us with all pipes <35% while conflicts/bytes/FETCH/LDS-size varied;
// R9's per-slab timing shows one ~39KB scattered window costs ~10K cycles of
// service, and with only ~2 windows in flight per CU that drain is exposed.
// R10 (pure gather, 175us) proved divergent per-lane gathers are TA-line-
// bound, so staging stays. Fix the one untested axis: 256-thread blocks,
// tile 8x8x16, window 14x14x32 = 24.5 KB -> 6 blocks/CU (24 waves), 9600
// blocks -> ~6 independent windows per CU at different convoy phases; drains
// overlap other blocks' compute/issue. All proven components verbatim:
// 16B global_load_lds + bits-2-4 z-XOR swizzle, f4 trf/out, z-quad per
// thread, clamped window + rare global fallback, chunked XCD swizzle.

#define NXD 160
#define NYD 192
#define NZD 160
#define NVOX (NXD * NYD * NZD)
#define NBATCH 2

#define TXT 8
#define TYT 8
#define TZT 16
#define LXT 14            // staged x extent (halo 3)
#define LYT 14            // staged y extent (halo 3)
#define LZT 32            // staged z extent (halo 8)
#define NROWS (LXT * LYT)          // 196 z-rows
#define LDS_N (NROWS * LZT)        // 6272 floats = 24.5 KB
#define NSLOT (NROWS * 8)          // 1568 16B staging slots

#define TILES_X (NXD / TXT)   // 20
#define TILES_Y (NYD / TYT)   // 24
#define TILES_Z (NZD / TZT)   // 10
#define NBLOCKS (NBATCH * TILES_X * TILES_Y * TILES_Z)   // 9600
#define BLK 256

typedef float f4 __attribute__((ext_vector_type(4)));

__global__ __launch_bounds__(BLK)
void warp3d_kernel(const float* __restrict__ vol,
                   const float* __restrict__ trf,
                   float* __restrict__ out) {
    __shared__ float tile[LDS_N];

    // chunked XCD swizzle (9600 % 8 == 0, bijective): each XCD gets a
    // contiguous run of 1200 tiles (tz fastest) -> window overlap in L2
    int bid0 = blockIdx.x;
    int bid = (bid0 & 7) * (NBLOCKS / 8) + (bid0 >> 3);

    int tz = bid % TILES_Z;
    int r  = bid / TILES_Z;
    int ty = r % TILES_Y;
    int r2 = r / TILES_Y;
    int tx = r2 % TILES_X;
    int b  = r2 / TILES_X;

    int x0t = tx * TXT, y0t = ty * TYT, z0t = tz * TZT;
    // clamped staging origin: window always fully inside the volume
    int lox = min(max(x0t - 3, 0), NXD - LXT);
    int loy = min(max(y0t - 3, 0), NYD - LYT);
    int loz = min(max(z0t - 8, 0), NZD - LZT);

    const float* vb = vol + (size_t)b * NVOX;

    int t = threadIdx.x;
    // compute-phase voxel quad: 4 z-consecutive voxels per thread (f4 I/O)
    int zq = t & 3;             // 4 z-quads
    int yq = (t >> 2) & 7;      // 8 y
    int xq = t >> 5;            // 8 x
    int x = x0t + xq, y = y0t + yq, zb0 = z0t + zq * 4;
    size_t vox_i = (((size_t)b * NXD + x) * NYD + y) * NZD + zb0;

    // prefetch trf (12 floats = 3 aligned float4) — overlaps staging latency
    const f4* trfv = (const f4*)(trf + vox_i * 3);
    f4 t0 = trfv[0], t1 = trfv[1], t2 = trfv[2];

    // ---- stage vol tile into LDS (16B async, bits-2-4 z-XOR swizzle) ----
    // slot = 16B unit; row = slot>>3 (one 32-fl z-row = 8 slots); dest linear
    // in slot (wave-uniform base + lane*16B); source z inverse-swizzled.
    {
        const float* gbase = vb + ((size_t)(lox * NYD + loy) * NZD + loz);
#pragma unroll
        for (int it = 0; it < 7; ++it) {
            int slot = it * BLK + t;
            if (slot < NSLOT) {          // masked lanes are a contiguous suffix
                int row = slot >> 3;
                int zg  = (slot & 7) << 2;
                int yi  = row % LYT;
                int xi  = row / LYT;
                int sz  = zg ^ ((yi & 7) << 2);   // involution, 16B-preserving
                const float* g = gbase + (size_t)xi * (NYD * NZD) + yi * NZD + sz;
                __builtin_amdgcn_global_load_lds(
                    (const __attribute__((address_space(1))) void*)g,
                    (__attribute__((address_space(3))) void*)&tile[slot * 4],
                    16, 0, 0);
            }
        }
    }
    __syncthreads();

    // ---- gather + trilinear blend, 4 voxels ----
    float dxa[4] = {t0.x, t0.w, t1.z, t2.y};
    float dya[4] = {t0.y, t1.x, t1.w, t2.z};
    float dza[4] = {t0.z, t1.y, t2.x, t2.w};

    float res[4];
#pragma unroll
    for (int j = 0; j < 4; ++j) {
        float lx = fminf(fmaxf((float)x + dxa[j], 0.0f), (float)(NXD - 1));
        float ly = fminf(fmaxf((float)y + dya[j], 0.0f), (float)(NYD - 1));
        float lz = fminf(fmaxf((float)(zb0 + j) + dza[j], 0.0f), (float)(NZD - 1));
        float fx = floorf(lx), fy = floorf(ly), fz = floorf(lz);
        int x0 = (int)fx, y0 = (int)fy, z0 = (int)fz;
        // lower-corner weights d1 = loc1 - loc (0 at clamped top border)
        float wx0 = fminf(fx + 1.0f, (float)(NXD - 1)) - lx;
        float wy0 = fminf(fy + 1.0f, (float)(NYD - 1)) - ly;
        float wz0 = fminf(fz + 1.0f, (float)(NZD - 1)) - lz;

        int ix = x0 - lox, iy = y0 - loy, iz = z0 - loz;
        bool ok = ((unsigned)ix <= LXT - 2) & ((unsigned)iy <= LYT - 2) &
                  ((unsigned)iz <= LZT - 2);
        int sx = ok ? ix : 0;            // safe LDS coords when !ok
        int sy = ok ? iy : 0;
        int sv = ok ? iz : 0;

        int base = (sx * LYT + sy) * LZT;
        int sw0 = (sy & 7) << 2;
        int sw1 = ((sy + 1) & 7) << 2;
        int A = base + (sv ^ sw0);                    // (y0, z0)
        int B = base + ((sv + 1) ^ sw0);              // (y0, z1)
        int C = base + LZT + (sv ^ sw1);              // (y1, z0)
        int D = base + LZT + ((sv + 1) ^ sw1);        // (y1, z1)

        float v000 = tile[A],              v001 = tile[B];
        float v010 = tile[C],              v011 = tile[D];
        float v100 = tile[A + LYT * LZT],  v101 = tile[B + LYT * LZT];
        float v110 = tile[C + LYT * LZT],  v111 = tile[D + LYT * LZT];

        if (!ok) {   // rare: sample outside staged window -> global gather
            int x1 = min(x0 + 1, NXD - 1);
            int y1 = min(y0 + 1, NYD - 1);
            int z1 = min(z0 + 1, NZD - 1);
            size_t o00 = (size_t)(x0 * NYD + y0) * NZD;
            size_t o01 = (size_t)(x0 * NYD + y1) * NZD;
            size_t o10 = (size_t)(x1 * NYD + y0) * NZD;
            size_t o11 = (size_t)(x1 * NYD + y1) * NZD;
            v000 = vb[o00 + z0]; v001 = vb[o00 + z1];
            v010 = vb[o01 + z0]; v011 = vb[o01 + z1];
            v100 = vb[o10 + z0]; v101 = vb[o10 + z1];
            v110 = vb[o11 + z0]; v111 = vb[o11 + z1];
        }

        float wx1 = 1.0f - wx0, wy1 = 1.0f - wy0, wz1 = 1.0f - wz0;
        res[j] = wx0 * (wy0 * (wz0 * v000 + wz1 * v001) +
                        wy1 * (wz0 * v010 + wz1 * v011)) +
                 wx1 * (wy0 * (wz0 * v100 + wz1 * v101) +
                        wy1 * (wz0 * v110 + wz1 * v111));
    }

    f4 o;
    o.x = res[0]; o.y = res[1]; o.z = res[2]; o.w = res[3];
    *(f4*)(out + vox_i) = o;
}

extern "C" void kernel_launch(void* const* d_in, const int* in_sizes, int n_in,
                              void* d_out, int out_size, void* d_ws, size_t ws_size,
                              hipStream_t stream) {
    const float* vol = (const float*)d_in[0];
    const float* trf = (const float*)d_in[1];
    float* out = (float*)d_out;

    warp3d_kernel<<<NBLOCKS, BLK, 0, stream>>>(vol, trf, out);
}